// Round 5
// baseline (819.027 us; speedup 1.0000x reference)
//
#include <hip/hip_runtime.h>
#include <math.h>

#define A_DIM 56
#define E_DIM 128

typedef short short8 __attribute__((ext_vector_type(8)));
typedef float floatx4 __attribute__((ext_vector_type(4)));

// ---------------- LDS layout (byte offsets, 16B-aligned) ----------------
// Single overlay region R [0, 38592): lifetimes are made disjoint by
// barriers (P1: read xT | barrier | write h;  P2: read h | barrier |
// reduce-buffers;  P3b: read x_row | barrier | write kmat).
#define XT_HI_B 0           // P0->P1: xT bf16 [134 rows=e+3][72 ushort pitch]
#define XT_LO_B 19296       //   ends 38592
#define H_HI_B  0           // P1->P2: h bf16 [62 rows=a+3][136 ushort pitch]
#define H_LO_B  16864       //   ends 33728
#define RB_B    0           // P2 reduce: 2 x 16KB partials (over dead h)
#define XR_HI_B 0           // P3a->P3b: x_row bf16 [56][136 ushort pitch]
#define XR_LO_B 15232       //   ends 30464
#define KM_B    0           // P3b->P4: kmat fp32 [56][132] = 29568
#define Q_B     33728       // P2->P3a (beyond h/RB extent)
#define QN_B    34240       // P3a->P4 (beyond x_row/kmat extent)
#define LG_B    34752       // P4->P6  (beyond kmat extent), 1920 B
#define DP_B    36672       // P6->P7, 960 B
#define LAM_B   38592       // P0->P6 (outside R; xT never touches it)
#define SMEM_B  38608

#define QF   (Q_B/4)
#define QNF  (QN_B/4)
#define LGF  (LG_B/4)
#define DPF  (DP_B/4)
#define LAMF (LAM_B/4)
#define KP2  132

// ---------------- workspace (ushort offsets) — fragment-ordered ----------
// W1: [tap7][kc2][nt4][lm16][lkg4][8]   a=nt*16+lm, ci=kc*32+lkg*8+j
#define W1H 0
#define W1L 28672
// W2: [tap7][kc4][mt8][lm16][lkg4][8]   eo=mt*16+lm, ei=kc*32+lkg*8+j
#define W2H 57344
#define W2L 172032
// WK: [kc4][mt8][lm16][lkg4][8]         o=mt*16+lm,  e=kc*32+lkg*8+j
#define WKH 286720
#define WKL 303104
#define PREP_ELEMS 159744   // 28672 + 114688 + 16384

__device__ __forceinline__ unsigned rne16(unsigned u) {
  return (u + 0x7FFFu + ((u >> 16) & 1u)) >> 16;
}
__device__ __forceinline__ unsigned pack_hi16(unsigned u0, unsigned u1) {
  return __builtin_amdgcn_perm(u1, u0, 0x07060302u);
}
__device__ __forceinline__ float silu_f(float v) { return v / (1.f + __expf(-v)); }

__global__ void prep_weights(const float* __restrict__ w_emb,
                             const float* __restrict__ w_atlas,
                             const float* __restrict__ w_k,
                             unsigned short* __restrict__ ws) {
  int idx = blockIdx.x * 256 + threadIdx.x;
  if (idx >= PREP_ELEMS) return;
  float v; int dst_hi, dst_lo;
  if (idx < 28672) {
    int tap = idx >> 12, kc = (idx >> 11) & 1, nt = (idx >> 9) & 3;
    int lm = (idx >> 5) & 15, lkg = (idx >> 3) & 3, jj = idx & 7;
    int a = nt * 16 + lm, ci = kc * 32 + lkg * 8 + jj;
    v = (a < A_DIM && ci < A_DIM) ? w_emb[(a * A_DIM + ci) * 7 + tap] : 0.f;
    dst_hi = W1H + idx; dst_lo = W1L + idx;
  } else if (idx < 143360) {
    int j = idx - 28672;
    int tap = j >> 14, kc = (j >> 12) & 3, mt = (j >> 9) & 7;
    int lm = (j >> 5) & 15, lkg = (j >> 3) & 3, jj = j & 7;
    int eo = mt * 16 + lm, ei = kc * 32 + lkg * 8 + jj;
    v = w_atlas[(eo * E_DIM + ei) * 7 + tap];
    dst_hi = W2H + j; dst_lo = W2L + j;
  } else {
    int j = idx - 143360;
    int kc = j >> 12, mt = (j >> 9) & 7;
    int lm = (j >> 5) & 15, lkg = (j >> 3) & 3, jj = j & 7;
    int o = mt * 16 + lm, e = kc * 32 + lkg * 8 + jj;
    v = w_k[o * E_DIM + e];
    dst_hi = WKH + j; dst_lo = WKL + j;
  }
  unsigned u = __float_as_uint(v);
  unsigned hi = rne16(u);
  float lof = v - __uint_as_float(hi << 16);
  unsigned lo = rne16(__float_as_uint(lof));
  ws[dst_hi] = (unsigned short)hi;
  ws[dst_lo] = (unsigned short)lo;
}

__global__ __launch_bounds__(256, 4)
void atlas_fused(const float* __restrict__ x,
                 const unsigned short* __restrict__ ws,
                 const float* __restrict__ b_emb, const float* __restrict__ b_atlas,
                 const float* __restrict__ qn_w,  const float* __restrict__ qn_b,
                 const float* __restrict__ kn_w,  const float* __restrict__ kn_b,
                 const float* __restrict__ lq1,   const float* __restrict__ lk1,
                 const float* __restrict__ lq2,   const float* __restrict__ lk2,
                 float* __restrict__ out)
{
  __shared__ __align__(16) unsigned char smem[SMEM_B];
  float* smf = (float*)smem;
  const int t = threadIdx.x;
  const int b = blockIdx.x;
  const int lane = t & 63;
  const int w = __builtin_amdgcn_readfirstlane(t >> 6);
  const int lm = lane & 15;
  const int lkg8 = (lane >> 4) * 8;      // k-run start within 32-chunk
  const int lr = (lane >> 4) * 4;        // C row base within tile

  const float* xb = x + (size_t)b * (A_DIM * E_DIM);

  // ====== Phase 0: zero xT pads, lambda, register-transpose stage of xT ===
  {
    uint4 z4 = make_uint4(0, 0, 0, 0);
    // xT pad: cols 56..63 for all 134 rows (hi+lo) -> 268 uint4
    //         rows {0,1,2,131,132,133} cols 0..55 (hi+lo) -> 84 uint4
    for (int i = t; i < 352; i += 256) {
      if (i < 268) {
        int arr = i & 1, row = i >> 1;
        *(uint4*)(smem + (arr ? XT_LO_B : XT_HI_B) + row * 144 + 112) = z4;
      } else {
        int j = i - 268;
        int arr = j / 42; j -= arr * 42;
        int rowi = j / 7, c = j - rowi * 7;
        int row = (rowi < 3) ? rowi : 128 + rowi;   // 0,1,2,131,132,133
        *(uint4*)(smem + (arr ? XT_LO_B : XT_HI_B) + row * 144 + c * 16) = z4;
      }
    }
    if (t == 0) {
      float s1 = 0.f, s2 = 0.f;
      for (int i = 0; i < 16; ++i) { s1 += lq1[i] * lk1[i]; s2 += lq2[i] * lk2[i]; }
      smf[LAMF] = expf(s1) - expf(s2) + 0.7f;
    }
    // transpose-stage: task (ab in 0..13, eb in 0..31), 4x4 block each
    int ab = t & 15;
    if (ab < 14) {
#pragma unroll
      for (int p = 0; p < 2; ++p) {
        int eb = (t >> 4) + 16 * p;
        floatx4 r0 = *(const floatx4*)(xb + (4 * ab + 0) * 128 + 4 * eb);
        floatx4 r1 = *(const floatx4*)(xb + (4 * ab + 1) * 128 + 4 * eb);
        floatx4 r2 = *(const floatx4*)(xb + (4 * ab + 2) * 128 + 4 * eb);
        floatx4 r3 = *(const floatx4*)(xb + (4 * ab + 3) * 128 + 4 * eb);
#pragma unroll
        for (int j2 = 0; j2 < 4; ++j2) {
          unsigned u0 = __float_as_uint(r0[j2]);
          unsigned u1 = __float_as_uint(r1[j2]);
          unsigned u2 = __float_as_uint(r2[j2]);
          unsigned u3 = __float_as_uint(r3[j2]);
          float l0 = r0[j2] - __uint_as_float(u0 & 0xFFFF0000u);
          float l1 = r1[j2] - __uint_as_float(u1 & 0xFFFF0000u);
          float l2 = r2[j2] - __uint_as_float(u2 & 0xFFFF0000u);
          float l3 = r3[j2] - __uint_as_float(u3 & 0xFFFF0000u);
          int off = (4 * eb + j2 + 3) * 144 + 8 * ab;
          *(uint2*)(smem + XT_HI_B + off) =
              make_uint2(pack_hi16(u0, u1), pack_hi16(u2, u3));
          *(uint2*)(smem + XT_LO_B + off) =
              make_uint2(pack_hi16(__float_as_uint(l0), __float_as_uint(l1)),
                         pack_hi16(__float_as_uint(l2), __float_as_uint(l3)));
        }
      }
    }
  }
  __syncthreads();

  // ================= Phase 1: conv1 (C1^T[e][a]) ===========================
  // A[m=e][k=ci] = xT (LDS hi/lo) ; B[k=ci][n=a] = W1 (global hi/lo)
  {
    floatx4 acc[2][4];
#pragma unroll
    for (int nt = 0; nt < 4; ++nt) {
      int a = nt * 16 + lm;
      float be = (a < A_DIM) ? b_emb[a] : 0.f;
#pragma unroll
      for (int mt = 0; mt < 2; ++mt) {
        acc[mt][nt][0] = be; acc[mt][nt][1] = be;
        acc[mt][nt][2] = be; acc[mt][nt][3] = be;
      }
    }
    const unsigned short* xh = (const unsigned short*)(smem + XT_HI_B);
    const unsigned short* xl = (const unsigned short*)(smem + XT_LO_B);
#pragma unroll 1
    for (int tap = 0; tap < 7; ++tap) {
      int arow0 = (32 * w + lm + tap) * 72;
      int arow1 = arow0 + 16 * 72;
#pragma unroll
      for (int kc = 0; kc < 2; ++kc) {
        int ko = kc * 32 + lkg8;
        const unsigned short* fb = ws + ((tap * 2 + kc) * 4) * 512 + lm * 32 + lkg8;
        short8 bh0 = *(const short8*)(fb + W1H);
        short8 bh1 = *(const short8*)(fb + W1H + 512);
        short8 bh2 = *(const short8*)(fb + W1H + 1024);
        short8 bh3 = *(const short8*)(fb + W1H + 1536);
        short8 bl0 = *(const short8*)(fb + W1L);
        short8 bl1 = *(const short8*)(fb + W1L + 512);
        short8 bl2 = *(const short8*)(fb + W1L + 1024);
        short8 bl3 = *(const short8*)(fb + W1L + 1536);
        short8 ah0 = *(const short8*)(xh + arow0 + ko);
        short8 ah1 = *(const short8*)(xh + arow1 + ko);
        short8 al0 = *(const short8*)(xl + arow0 + ko);
        short8 al1 = *(const short8*)(xl + arow1 + ko);
        short8 bh[4] = {bh0, bh1, bh2, bh3};
        short8 bl[4] = {bl0, bl1, bl2, bl3};
#pragma unroll
        for (int nt = 0; nt < 4; ++nt) {
          acc[0][nt] = __builtin_amdgcn_mfma_f32_16x16x32_bf16(ah0, bh[nt], acc[0][nt], 0, 0, 0);
          acc[0][nt] = __builtin_amdgcn_mfma_f32_16x16x32_bf16(al0, bh[nt], acc[0][nt], 0, 0, 0);
          acc[0][nt] = __builtin_amdgcn_mfma_f32_16x16x32_bf16(ah0, bl[nt], acc[0][nt], 0, 0, 0);
          acc[1][nt] = __builtin_amdgcn_mfma_f32_16x16x32_bf16(ah1, bh[nt], acc[1][nt], 0, 0, 0);
          acc[1][nt] = __builtin_amdgcn_mfma_f32_16x16x32_bf16(al1, bh[nt], acc[1][nt], 0, 0, 0);
          acc[1][nt] = __builtin_amdgcn_mfma_f32_16x16x32_bf16(ah1, bl[nt], acc[1][nt], 0, 0, 0);
        }
      }
    }
    // ---- xT is dead once ALL waves finished their reads; h overlays it ----
    __syncthreads();
    // zero h pad rows {0,1,2,59,60,61}: 204 uint4
    {
      uint4 z4 = make_uint4(0, 0, 0, 0);
      for (int i = t; i < 204; i += 256) {
        int arr = i / 102, j = i - arr * 102;
        int r6 = j / 17, c = j - r6 * 17;
        int row = (r6 < 3) ? r6 : 56 + r6;
        *(uint4*)(smem + (arr ? H_LO_B : H_HI_B) + row * 272 + c * 16) = z4;
      }
    }
    // epilogue: SiLU, split hi/lo, write h[a+3][e] (4 consecutive e per lane)
#pragma unroll
    for (int mt = 0; mt < 2; ++mt) {
      int e0 = 16 * (2 * w + mt) + lr;
#pragma unroll
      for (int nt = 0; nt < 4; ++nt) {
        int a = 16 * nt + lm;
        if (a < A_DIM) {
          float v0 = silu_f(acc[mt][nt][0]), v1 = silu_f(acc[mt][nt][1]);
          float v2 = silu_f(acc[mt][nt][2]), v3 = silu_f(acc[mt][nt][3]);
          unsigned u0 = __float_as_uint(v0), u1 = __float_as_uint(v1);
          unsigned u2 = __float_as_uint(v2), u3 = __float_as_uint(v3);
          float l0 = v0 - __uint_as_float(u0 & 0xFFFF0000u);
          float l1 = v1 - __uint_as_float(u1 & 0xFFFF0000u);
          float l2 = v2 - __uint_as_float(u2 & 0xFFFF0000u);
          float l3 = v3 - __uint_as_float(u3 & 0xFFFF0000u);
          int off = (a + 3) * 272 + e0 * 2;
          *(uint2*)(smem + H_HI_B + off) = make_uint2(pack_hi16(u0, u1), pack_hi16(u2, u3));
          *(uint2*)(smem + H_LO_B + off) =
              make_uint2(pack_hi16(__float_as_uint(l0), __float_as_uint(l1)),
                         pack_hi16(__float_as_uint(l2), __float_as_uint(l3)));
        }
      }
    }
  }
  __syncthreads();

  // ====== Phase 2: conv2 (C2[eo][a]) + mean -> q, K-split x eo-split ======
  // Wave w: K-group g=w>>1 (kc in {2g,2g+1}), eo-half p=w&1 (eo in [64p,64p+64)).
  // Each wave reads only HALF of h (B-reads 224 -> 112/wave); partials are
  // reduced across the wave pair (g=0,g=1) through LDS over the dead h region.
  {
    const int g = w >> 1, p = w & 1;
    floatx4 acc[4][4];
#pragma unroll
    for (int mt = 0; mt < 4; ++mt)
#pragma unroll
      for (int nt = 0; nt < 4; ++nt) {
        acc[mt][nt][0] = 0.f; acc[mt][nt][1] = 0.f;
        acc[mt][nt][2] = 0.f; acc[mt][nt][3] = 0.f;
      }
    const unsigned char* hh = smem + H_HI_B;
    const unsigned char* hl = smem + H_LO_B;
#pragma unroll 1
    for (int tap = 0; tap < 7; ++tap) {
      int rofs[4];
#pragma unroll
      for (int nt = 0; nt < 4; ++nt) {
        int r = 16 * nt + lm + tap;
        rofs[nt] = ((r > 61) ? 61 : r) * 272;   // clamp touches only a>=56 (discarded)
      }
#pragma unroll
      for (int kc2 = 0; kc2 < 2; ++kc2) {
        int kc = 2 * g + kc2;
        int kob = (kc * 32 + lkg8) * 2;
        short8 bh[4], bl[4];
#pragma unroll
        for (int nt = 0; nt < 4; ++nt) {
          bh[nt] = *(const short8*)(hh + rofs[nt] + kob);
          bl[nt] = *(const short8*)(hl + rofs[nt] + kob);
        }
        const unsigned short* fb0 =
            ws + ((tap * 4 + kc) * 8 + 4 * p) * 512 + lm * 32 + lkg8;
#pragma unroll
        for (int mt = 0; mt < 4; ++mt) {
          short8 ah = *(const short8*)(fb0 + W2H + mt * 512);
          short8 al = *(const short8*)(fb0 + W2L + mt * 512);
#pragma unroll
          for (int nt = 0; nt < 4; ++nt) {
            acc[mt][nt] = __builtin_amdgcn_mfma_f32_16x16x32_bf16(ah, bh[nt], acc[mt][nt], 0, 0, 0);
            acc[mt][nt] = __builtin_amdgcn_mfma_f32_16x16x32_bf16(al, bh[nt], acc[mt][nt], 0, 0, 0);
            acc[mt][nt] = __builtin_amdgcn_mfma_f32_16x16x32_bf16(ah, bl[nt], acc[mt][nt], 0, 0, 0);
          }
        }
      }
    }
    __syncthreads();     // all B-reads done -> h dead; RB overlays it
    float* rb = (float*)(smem + RB_B + p * 16384);
    if (g == 1) {        // dump partials (lane-contiguous, conflict-free)
#pragma unroll
      for (int mt = 0; mt < 4; ++mt)
#pragma unroll
        for (int nt = 0; nt < 4; ++nt)
          *(floatx4*)(rb + ((mt * 4 + nt) * 64 + lane) * 4) = acc[mt][nt];
    }
    __syncthreads();
    if (g == 0) {        // add partner partial + bias, SiLU, mean over a
#pragma unroll
      for (int mt = 0; mt < 4; ++mt) {
        int eo0 = 64 * p + 16 * mt + lr;
        floatx4 bias4;
        bias4[0] = b_atlas[eo0];     bias4[1] = b_atlas[eo0 + 1];
        bias4[2] = b_atlas[eo0 + 2]; bias4[3] = b_atlas[eo0 + 3];
        floatx4 tot[4];
#pragma unroll
        for (int nt = 0; nt < 4; ++nt) {
          floatx4 part = *(const floatx4*)(rb + ((mt * 4 + nt) * 64 + lane) * 4);
          tot[nt] = acc[mt][nt] + part + bias4;
        }
#pragma unroll
        for (int r = 0; r < 4; ++r) {
          float s = 0.f;
#pragma unroll
          for (int nt = 0; nt < 4; ++nt) {
            float v = silu_f(tot[nt][r]);
            int a = 16 * nt + lm;
            s += (a < A_DIM) ? v : 0.f;
          }
          s += __shfl_xor(s, 1, 64);
          s += __shfl_xor(s, 2, 64);
          s += __shfl_xor(s, 4, 64);
          s += __shfl_xor(s, 8, 64);
          if (lm == 0) smf[QF + eo0 + r] = s * (1.f / 56.f);
        }
      }
    }
  }
  __syncthreads();

  // ====== Phase 3a: LN(q) (t<128) + stage x rows hi/lo over dead h ========
  if (t < 128) {
    float v = smf[QF + t];
    float s = v;
#pragma unroll
    for (int m = 1; m < 16; m <<= 1) s += __shfl_xor(s, m, 64);
    float mean = s * (1.f / 16.f);
    float d = v - mean;
    float s2 = d * d;
#pragma unroll
    for (int m = 1; m < 16; m <<= 1) s2 += __shfl_xor(s2, m, 64);
    float var = s2 * (1.f / 16.f);
    int dd = t & 15;
    float qn = d * rsqrtf(var + 1e-5f) * qn_w[dd] + qn_b[dd];
    smf[QNF + t] = qn * 0.25f;                 // SCALING = 16^-0.5
  }
  for (int i = t; i < 1792; i += 256) {        // x_row: [a][e] bf16 hi/lo
    int a = i >> 5, e4 = i & 31;
    float4 v = *(const float4*)(xb + a * 128 + e4 * 4);
    unsigned u0 = __float_as_uint(v.x), u1 = __float_as_uint(v.y);
    unsigned u2 = __float_as_uint(v.z), u3 = __float_as_uint(v.w);
    float l0 = v.x - __uint_as_float(u0 & 0xFFFF0000u);
    float l1 = v.y - __uint_as_float(u1 & 0xFFFF0000u);
    float l2 = v.z - __uint_as_float(u2 & 0xFFFF0000u);
    float l3 = v.w - __uint_as_float(u3 & 0xFFFF0000u);
    int off = a * 272 + e4 * 8;
    *(uint2*)(smem + XR_HI_B + off) = make_uint2(pack_hi16(u0, u1), pack_hi16(u2, u3));
    *(uint2*)(smem + XR_LO_B + off) =
        make_uint2(pack_hi16(__float_as_uint(l0), __float_as_uint(l1)),
                   pack_hi16(__float_as_uint(l2), __float_as_uint(l3)));
  }
  __syncthreads();

  // ================= Phase 3b: k-proj (C3^T[o][a]) -> kmat[a][o] ===========
  // A[m=o][k=e] = WK (global hi/lo) ; B[n=a][k=e] = x_row (LDS hi/lo)
  {
    floatx4 acc[2][4];
#pragma unroll
    for (int mt = 0; mt < 2; ++mt)
#pragma unroll
      for (int nt = 0; nt < 4; ++nt) {
        acc[mt][nt][0] = 0.f; acc[mt][nt][1] = 0.f;
        acc[mt][nt][2] = 0.f; acc[mt][nt][3] = 0.f;
      }
    const unsigned char* xrh = smem + XR_HI_B;
    const unsigned char* xrl = smem + XR_LO_B;
    int rofs[4];
#pragma unroll
    for (int nt = 0; nt < 4; ++nt) {
      int a = 16 * nt + lm;
      rofs[nt] = ((a > 55) ? 55 : a) * 272;
    }
#pragma unroll 1
    for (int kc = 0; kc < 4; ++kc) {
      int kob = (kc * 32 + lkg8) * 2;
      const unsigned short* fb = ws + (kc * 8 + 2 * w) * 512 + lm * 32 + lkg8;
      short8 ah0 = *(const short8*)(fb + WKH);
      short8 ah1 = *(const short8*)(fb + WKH + 512);
      short8 al0 = *(const short8*)(fb + WKL);
      short8 al1 = *(const short8*)(fb + WKL + 512);
      short8 bh[4], bl[4];
#pragma unroll
      for (int nt = 0; nt < 4; ++nt) {
        bh[nt] = *(const short8*)(xrh + rofs[nt] + kob);
        bl[nt] = *(const short8*)(xrl + rofs[nt] + kob);
      }
#pragma unroll
      for (int nt = 0; nt < 4; ++nt) {
        acc[0][nt] = __builtin_amdgcn_mfma_f32_16x16x32_bf16(ah0, bh[nt], acc[0][nt], 0, 0, 0);
        acc[0][nt] = __builtin_amdgcn_mfma_f32_16x16x32_bf16(al0, bh[nt], acc[0][nt], 0, 0, 0);
        acc[0][nt] = __builtin_amdgcn_mfma_f32_16x16x32_bf16(ah0, bl[nt], acc[0][nt], 0, 0, 0);
        acc[1][nt] = __builtin_amdgcn_mfma_f32_16x16x32_bf16(ah1, bh[nt], acc[1][nt], 0, 0, 0);
        acc[1][nt] = __builtin_amdgcn_mfma_f32_16x16x32_bf16(al1, bh[nt], acc[1][nt], 0, 0, 0);
        acc[1][nt] = __builtin_amdgcn_mfma_f32_16x16x32_bf16(ah1, bl[nt], acc[1][nt], 0, 0, 0);
      }
    }
    // ---- x_row dead once ALL waves finished reads; kmat overlays it -------
    __syncthreads();
#pragma unroll
    for (int mt = 0; mt < 2; ++mt) {
      int o0 = 16 * (2 * w + mt) + lr;
#pragma unroll
      for (int nt = 0; nt < 4; ++nt) {
        int a = 16 * nt + lm;
        if (a < A_DIM)
          *(floatx4*)&smf[(KM_B / 4) + a * KP2 + o0] = acc[mt][nt];
      }
    }
  }
  __syncthreads();

  // ================= Phase 4: layernorm(k) + logit = qn . kn ===============
  for (int r = 0; r < 2; ++r) {
    int task = t + r * 256;
    if (task < A_DIM * 8) {
      int a = task >> 3, h2 = task & 7;
      float kv[16];
      float s = 0.f;
#pragma unroll
      for (int d = 0; d < 16; ++d) { kv[d] = smf[(KM_B / 4) + a * KP2 + h2 * 16 + d]; s += kv[d]; }
      float mean = s * (1.f / 16.f);
      float s2 = 0.f;
#pragma unroll
      for (int d = 0; d < 16; ++d) { float dd = kv[d] - mean; s2 += dd * dd; }
      float rs = rsqrtf(s2 * (1.f / 16.f) + 1e-5f);
      float logit = 0.f;
#pragma unroll
      for (int d = 0; d < 16; ++d) {
        float kn = (kv[d] - mean) * rs * kn_w[d] + kn_b[d];
        logit += smf[QNF + h2 * 16 + d] * kn;
      }
      smf[LGF + h2 * 60 + a] = logit;
    }
  }
  __syncthreads();

  // ================= Phase 5: softmax over a per head2 =====================
  {
    int g = t >> 5;
    int l = t & 31;
    float v0 = smf[LGF + g * 60 + l];
    bool has1 = (l < A_DIM - 32);
    float v1 = has1 ? smf[LGF + g * 60 + 32 + l] : -1e30f;
    float m = fmaxf(v0, v1);
#pragma unroll
    for (int s = 1; s < 32; s <<= 1) m = fmaxf(m, __shfl_xor(m, s, 64));
    float e0 = expf(v0 - m);
    float e1 = has1 ? expf(v1 - m) : 0.f;
    float ssum = e0 + e1;
#pragma unroll
    for (int s = 1; s < 32; s <<= 1) ssum += __shfl_xor(ssum, s, 64);
    float inv = 1.f / ssum;
    smf[LGF + g * 60 + l] = e0 * inv;
    if (has1) smf[LGF + g * 60 + 32 + l] = e1 * inv;
  }
  __syncthreads();

  // ================= Phase 6: diff softmax per head h ======================
  {
    int h = t >> 6;
    int a = t & 63;
    float lam = smf[LAMF];
    float dlog = -1e30f;
    if (a < A_DIM) {
      float p0 = smf[LGF + (2 * h) * 60 + a];
      float p1 = smf[LGF + (2 * h + 1) * 60 + a];
      dlog = p0 - lam * p1;
    }
    float m = dlog;
#pragma unroll
    for (int s = 1; s < 64; s <<= 1) m = fmaxf(m, __shfl_xor(m, s, 64));
    float e = (a < A_DIM) ? expf(dlog - m) : 0.f;
    float ss = e;
#pragma unroll
    for (int s = 1; s < 64; s <<= 1) ss += __shfl_xor(ss, s, 64);
    if (a < A_DIM) smf[DPF + h * 60 + a] = e / ss;
  }
  __syncthreads();

  // ================= Phase 7: mean over heads ==============================
  if (t < A_DIM) {
    float r = 0.25f * (smf[DPF + t] + smf[DPF + 60 + t] +
                       smf[DPF + 120 + t] + smf[DPF + 180 + t]);
    out[(size_t)b * A_DIM + t] = r;
  }
}

extern "C" void kernel_launch(void* const* d_in, const int* in_sizes, int n_in,
                              void* d_out, int out_size, void* d_ws, size_t ws_size,
                              hipStream_t stream) {
  const float* x       = (const float*)d_in[0];
  const float* w_emb   = (const float*)d_in[1];
  const float* b_emb   = (const float*)d_in[2];
  const float* w_atlas = (const float*)d_in[3];
  const float* b_atlas = (const float*)d_in[4];
  const float* w_k     = (const float*)d_in[5];
  const float* qn_w    = (const float*)d_in[6];
  const float* qn_b    = (const float*)d_in[7];
  const float* kn_w    = (const float*)d_in[8];
  const float* kn_b    = (const float*)d_in[9];
  const float* lq1     = (const float*)d_in[10];
  const float* lk1     = (const float*)d_in[11];
  const float* lq2     = (const float*)d_in[12];
  const float* lk2     = (const float*)d_in[13];
  float* out = (float*)d_out;
  unsigned short* ws = (unsigned short*)d_ws;

  prep_weights<<<dim3((PREP_ELEMS + 255) / 256), dim3(256), 0, stream>>>(
      w_emb, w_atlas, w_k, ws);

  const int Bn = in_sizes[0] / (A_DIM * E_DIM);   // 8192
  atlas_fused<<<dim3(Bn), dim3(256), 0, stream>>>(
      x, ws, b_emb, b_atlas, qn_w, qn_b, kn_w, kn_b,
      lq1, lk1, lq2, lk2, out);
}

// Round 6
// 793.255 us; speedup vs baseline: 1.0325x; 1.0325x over previous
//
#include <hip/hip_runtime.h>
#include <math.h>

#define A_DIM 56
#define E_DIM 128

typedef short short8 __attribute__((ext_vector_type(8)));
typedef float floatx4 __attribute__((ext_vector_type(4)));

// ---------------- LDS layout (byte offsets, 16B-aligned) ----------------
// Single overlay region R [0, 38592): lifetimes are made disjoint by
// barriers (P1: read xT | barrier | write h;  P3b: read x_row | barrier |
// write kmat).  Tail scalars live in R's slack beyond each tenant's extent.
#define XT_HI_B 0           // P0->P1: xT bf16 [134 rows=e+3][72 ushort pitch]
#define XT_LO_B 19296       //   ends 38592
#define H_HI_B  0           // P1->P2: h bf16 [62 rows=a+3][136 ushort pitch]
#define H_LO_B  16864       //   ends 33728
#define XR_HI_B 0           // P3a->P3b: x_row bf16 [56][136 ushort pitch]
#define XR_LO_B 15232       //   ends 30464
#define KM_B    0           // P3b->P4: kmat fp32 [56][132] = 29568
#define Q_B     33728       // P2->P3a (beyond h extent)
#define QN_B    34240       // P3a->P4 (beyond x_row/kmat extent)
#define LG_B    34752       // P4->P5  (beyond kmat extent), 1920 B
#define DP_B    36672       // P56->P7, 960 B
#define LAM_B   38592       // P0->P56 (outside R)
#define SMEM_B  38608

#define QF   (Q_B/4)
#define QNF  (QN_B/4)
#define LGF  (LG_B/4)
#define DPF  (DP_B/4)
#define LAMF (LAM_B/4)
#define KP2  132

// ---------------- workspace (ushort offsets) — fragment-ordered ----------
// W1: [tap7][kc2][nt4][lm16][lkg4][8]   a=nt*16+lm, ci=kc*32+lkg*8+j
#define W1H 0
#define W1L 28672
// W2: [tap7][kc4][mt8][lm16][lkg4][8]   eo=mt*16+lm, ei=kc*32+lkg*8+j
#define W2H 57344
#define W2L 172032
// WK: [kc4][mt8][lm16][lkg4][8]         o=mt*16+lm,  e=kc*32+lkg*8+j
#define WKH 286720
#define WKL 303104
#define PREP_ELEMS 159744   // 28672 + 114688 + 16384

__device__ __forceinline__ unsigned rne16(unsigned u) {
  return (u + 0x7FFFu + ((u >> 16) & 1u)) >> 16;
}
__device__ __forceinline__ unsigned pack_hi16(unsigned u0, unsigned u1) {
  return __builtin_amdgcn_perm(u1, u0, 0x07060302u);
}
__device__ __forceinline__ float silu_f(float v) { return v / (1.f + __expf(-v)); }

__global__ void prep_weights(const float* __restrict__ w_emb,
                             const float* __restrict__ w_atlas,
                             const float* __restrict__ w_k,
                             unsigned short* __restrict__ ws) {
  int idx = blockIdx.x * 256 + threadIdx.x;
  if (idx >= PREP_ELEMS) return;
  float v; int dst_hi, dst_lo;
  if (idx < 28672) {
    int tap = idx >> 12, kc = (idx >> 11) & 1, nt = (idx >> 9) & 3;
    int lm = (idx >> 5) & 15, lkg = (idx >> 3) & 3, jj = idx & 7;
    int a = nt * 16 + lm, ci = kc * 32 + lkg * 8 + jj;
    v = (a < A_DIM && ci < A_DIM) ? w_emb[(a * A_DIM + ci) * 7 + tap] : 0.f;
    dst_hi = W1H + idx; dst_lo = W1L + idx;
  } else if (idx < 143360) {
    int j = idx - 28672;
    int tap = j >> 14, kc = (j >> 12) & 3, mt = (j >> 9) & 7;
    int lm = (j >> 5) & 15, lkg = (j >> 3) & 3, jj = j & 7;
    int eo = mt * 16 + lm, ei = kc * 32 + lkg * 8 + jj;
    v = w_atlas[(eo * E_DIM + ei) * 7 + tap];
    dst_hi = W2H + j; dst_lo = W2L + j;
  } else {
    int j = idx - 143360;
    int kc = j >> 12, mt = (j >> 9) & 7;
    int lm = (j >> 5) & 15, lkg = (j >> 3) & 3, jj = j & 7;
    int o = mt * 16 + lm, e = kc * 32 + lkg * 8 + jj;
    v = w_k[o * E_DIM + e];
    dst_hi = WKH + j; dst_lo = WKL + j;
  }
  unsigned u = __float_as_uint(v);
  unsigned hi = rne16(u);
  float lof = v - __uint_as_float(hi << 16);
  unsigned lo = rne16(__float_as_uint(lof));
  ws[dst_hi] = (unsigned short)hi;
  ws[dst_lo] = (unsigned short)lo;
}

__global__ __launch_bounds__(256, 4)
void atlas_fused(const float* __restrict__ x,
                 const unsigned short* __restrict__ ws,
                 const float* __restrict__ b_emb, const float* __restrict__ b_atlas,
                 const float* __restrict__ qn_w,  const float* __restrict__ qn_b,
                 const float* __restrict__ kn_w,  const float* __restrict__ kn_b,
                 const float* __restrict__ lq1,   const float* __restrict__ lk1,
                 const float* __restrict__ lq2,   const float* __restrict__ lk2,
                 float* __restrict__ out)
{
  __shared__ __align__(16) unsigned char smem[SMEM_B];
  float* smf = (float*)smem;
  const int t = threadIdx.x;
  const int b = blockIdx.x;
  const int lane = t & 63;
  const int w = __builtin_amdgcn_readfirstlane(t >> 6);
  const int lm = lane & 15;
  const int lkg8 = (lane >> 4) * 8;      // k-run start within 32-chunk
  const int lr = (lane >> 4) * 4;        // C row base within tile

  const float* xb = x + (size_t)b * (A_DIM * E_DIM);

  // ====== Phase 0: zero xT pads, lambda, register-transpose stage of xT ===
  {
    uint4 z4 = make_uint4(0, 0, 0, 0);
    for (int i = t; i < 352; i += 256) {
      if (i < 268) {
        int arr = i & 1, row = i >> 1;
        *(uint4*)(smem + (arr ? XT_LO_B : XT_HI_B) + row * 144 + 112) = z4;
      } else {
        int j = i - 268;
        int arr = j / 42; j -= arr * 42;
        int rowi = j / 7, c = j - rowi * 7;
        int row = (rowi < 3) ? rowi : 128 + rowi;   // 0,1,2,131,132,133
        *(uint4*)(smem + (arr ? XT_LO_B : XT_HI_B) + row * 144 + c * 16) = z4;
      }
    }
    if (t == 0) {
      float s1 = 0.f, s2 = 0.f;
      for (int i = 0; i < 16; ++i) { s1 += lq1[i] * lk1[i]; s2 += lq2[i] * lk2[i]; }
      smf[LAMF] = expf(s1) - expf(s2) + 0.7f;
    }
    // transpose-stage: task (ab in 0..13, eb in 0..31), 4x4 block each
    int ab = t & 15;
    if (ab < 14) {
#pragma unroll
      for (int p = 0; p < 2; ++p) {
        int eb = (t >> 4) + 16 * p;
        floatx4 r0 = *(const floatx4*)(xb + (4 * ab + 0) * 128 + 4 * eb);
        floatx4 r1 = *(const floatx4*)(xb + (4 * ab + 1) * 128 + 4 * eb);
        floatx4 r2 = *(const floatx4*)(xb + (4 * ab + 2) * 128 + 4 * eb);
        floatx4 r3 = *(const floatx4*)(xb + (4 * ab + 3) * 128 + 4 * eb);
#pragma unroll
        for (int j2 = 0; j2 < 4; ++j2) {
          unsigned u0 = __float_as_uint(r0[j2]);
          unsigned u1 = __float_as_uint(r1[j2]);
          unsigned u2 = __float_as_uint(r2[j2]);
          unsigned u3 = __float_as_uint(r3[j2]);
          float l0 = r0[j2] - __uint_as_float(u0 & 0xFFFF0000u);
          float l1 = r1[j2] - __uint_as_float(u1 & 0xFFFF0000u);
          float l2 = r2[j2] - __uint_as_float(u2 & 0xFFFF0000u);
          float l3 = r3[j2] - __uint_as_float(u3 & 0xFFFF0000u);
          int off = (4 * eb + j2 + 3) * 144 + 8 * ab;
          *(uint2*)(smem + XT_HI_B + off) =
              make_uint2(pack_hi16(u0, u1), pack_hi16(u2, u3));
          *(uint2*)(smem + XT_LO_B + off) =
              make_uint2(pack_hi16(__float_as_uint(l0), __float_as_uint(l1)),
                         pack_hi16(__float_as_uint(l2), __float_as_uint(l3)));
        }
      }
    }
  }
  __syncthreads();

  // ================= Phase 1: conv1 (C1^T[e][a]) ===========================
  // A[m=e][k=ci] = xT (LDS hi/lo) ; B[k=ci][n=a] = W1 (global hi/lo)
  {
    floatx4 acc[2][4];
#pragma unroll
    for (int nt = 0; nt < 4; ++nt) {
      int a = nt * 16 + lm;
      float be = (a < A_DIM) ? b_emb[a] : 0.f;
#pragma unroll
      for (int mt = 0; mt < 2; ++mt) {
        acc[mt][nt][0] = be; acc[mt][nt][1] = be;
        acc[mt][nt][2] = be; acc[mt][nt][3] = be;
      }
    }
    const unsigned short* xh = (const unsigned short*)(smem + XT_HI_B);
    const unsigned short* xl = (const unsigned short*)(smem + XT_LO_B);
    __builtin_amdgcn_s_setprio(1);
#pragma unroll 1
    for (int tap = 0; tap < 7; ++tap) {
      int arow0 = (32 * w + lm + tap) * 72;
      int arow1 = arow0 + 16 * 72;
#pragma unroll
      for (int kc = 0; kc < 2; ++kc) {
        int ko = kc * 32 + lkg8;
        const unsigned short* fb = ws + ((tap * 2 + kc) * 4) * 512 + lm * 32 + lkg8;
        short8 bh0 = *(const short8*)(fb + W1H);
        short8 bh1 = *(const short8*)(fb + W1H + 512);
        short8 bh2 = *(const short8*)(fb + W1H + 1024);
        short8 bh3 = *(const short8*)(fb + W1H + 1536);
        short8 bl0 = *(const short8*)(fb + W1L);
        short8 bl1 = *(const short8*)(fb + W1L + 512);
        short8 bl2 = *(const short8*)(fb + W1L + 1024);
        short8 bl3 = *(const short8*)(fb + W1L + 1536);
        short8 ah0 = *(const short8*)(xh + arow0 + ko);
        short8 ah1 = *(const short8*)(xh + arow1 + ko);
        short8 al0 = *(const short8*)(xl + arow0 + ko);
        short8 al1 = *(const short8*)(xl + arow1 + ko);
        short8 bh[4] = {bh0, bh1, bh2, bh3};
        short8 bl[4] = {bl0, bl1, bl2, bl3};
#pragma unroll
        for (int nt = 0; nt < 4; ++nt) {
          acc[0][nt] = __builtin_amdgcn_mfma_f32_16x16x32_bf16(ah0, bh[nt], acc[0][nt], 0, 0, 0);
          acc[0][nt] = __builtin_amdgcn_mfma_f32_16x16x32_bf16(al0, bh[nt], acc[0][nt], 0, 0, 0);
          acc[0][nt] = __builtin_amdgcn_mfma_f32_16x16x32_bf16(ah0, bl[nt], acc[0][nt], 0, 0, 0);
          acc[1][nt] = __builtin_amdgcn_mfma_f32_16x16x32_bf16(ah1, bh[nt], acc[1][nt], 0, 0, 0);
          acc[1][nt] = __builtin_amdgcn_mfma_f32_16x16x32_bf16(al1, bh[nt], acc[1][nt], 0, 0, 0);
          acc[1][nt] = __builtin_amdgcn_mfma_f32_16x16x32_bf16(ah1, bl[nt], acc[1][nt], 0, 0, 0);
        }
      }
    }
    __builtin_amdgcn_s_setprio(0);
    // ---- xT is dead once ALL waves finished their reads; h overlays it ----
    __syncthreads();
    // zero h pad rows {0,1,2,59,60,61}: 204 uint4
    {
      uint4 z4 = make_uint4(0, 0, 0, 0);
      for (int i = t; i < 204; i += 256) {
        int arr = i / 102, j = i - arr * 102;
        int r6 = j / 17, c = j - r6 * 17;
        int row = (r6 < 3) ? r6 : 56 + r6;
        *(uint4*)(smem + (arr ? H_LO_B : H_HI_B) + row * 272 + c * 16) = z4;
      }
    }
    // epilogue: SiLU, split hi/lo, write h[a+3][e] (4 consecutive e per lane)
#pragma unroll
    for (int mt = 0; mt < 2; ++mt) {
      int e0 = 16 * (2 * w + mt) + lr;
#pragma unroll
      for (int nt = 0; nt < 4; ++nt) {
        int a = 16 * nt + lm;
        if (a < A_DIM) {
          float v0 = silu_f(acc[mt][nt][0]), v1 = silu_f(acc[mt][nt][1]);
          float v2 = silu_f(acc[mt][nt][2]), v3 = silu_f(acc[mt][nt][3]);
          unsigned u0 = __float_as_uint(v0), u1 = __float_as_uint(v1);
          unsigned u2 = __float_as_uint(v2), u3 = __float_as_uint(v3);
          float l0 = v0 - __uint_as_float(u0 & 0xFFFF0000u);
          float l1 = v1 - __uint_as_float(u1 & 0xFFFF0000u);
          float l2 = v2 - __uint_as_float(u2 & 0xFFFF0000u);
          float l3 = v3 - __uint_as_float(u3 & 0xFFFF0000u);
          int off = (a + 3) * 272 + e0 * 2;
          *(uint2*)(smem + H_HI_B + off) = make_uint2(pack_hi16(u0, u1), pack_hi16(u2, u3));
          *(uint2*)(smem + H_LO_B + off) =
              make_uint2(pack_hi16(__float_as_uint(l0), __float_as_uint(l1)),
                         pack_hi16(__float_as_uint(l2), __float_as_uint(l3)));
        }
      }
    }
  }
  __syncthreads();

  // ================= Phase 2: conv2 (C2[eo][a]) + mean over a -> q =========
  // (round-4 form: eo-quarter per wave, acc[2][4] — no spill)
  {
    floatx4 acc[2][4];
#pragma unroll
    for (int mt = 0; mt < 2; ++mt) {
      int eo0 = 16 * (2 * w + mt) + lr;
      float c0 = b_atlas[eo0], c1 = b_atlas[eo0 + 1];
      float c2 = b_atlas[eo0 + 2], c3 = b_atlas[eo0 + 3];
#pragma unroll
      for (int nt = 0; nt < 4; ++nt) {
        acc[mt][nt][0] = c0; acc[mt][nt][1] = c1;
        acc[mt][nt][2] = c2; acc[mt][nt][3] = c3;
      }
    }
    const unsigned char* hh = smem + H_HI_B;
    const unsigned char* hl = smem + H_LO_B;
    __builtin_amdgcn_s_setprio(1);
#pragma unroll 1
    for (int tap = 0; tap < 7; ++tap) {
      int rofs[4];
#pragma unroll
      for (int nt = 0; nt < 4; ++nt) {
        int r = 16 * nt + lm + tap;
        rofs[nt] = ((r > 61) ? 61 : r) * 272;   // clamp touches only a>=56 (discarded)
      }
#pragma unroll
      for (int kc = 0; kc < 4; ++kc) {
        int kob = (kc * 32 + lkg8) * 2;
        const unsigned short* fb = ws + ((tap * 4 + kc) * 8 + 2 * w) * 512 + lm * 32 + lkg8;
        short8 ah0 = *(const short8*)(fb + W2H);
        short8 ah1 = *(const short8*)(fb + W2H + 512);
        short8 al0 = *(const short8*)(fb + W2L);
        short8 al1 = *(const short8*)(fb + W2L + 512);
        short8 bh[4], bl[4];
#pragma unroll
        for (int nt = 0; nt < 4; ++nt) {
          bh[nt] = *(const short8*)(hh + rofs[nt] + kob);
          bl[nt] = *(const short8*)(hl + rofs[nt] + kob);
        }
#pragma unroll
        for (int nt = 0; nt < 4; ++nt) {
          acc[0][nt] = __builtin_amdgcn_mfma_f32_16x16x32_bf16(ah0, bh[nt], acc[0][nt], 0, 0, 0);
          acc[0][nt] = __builtin_amdgcn_mfma_f32_16x16x32_bf16(al0, bh[nt], acc[0][nt], 0, 0, 0);
          acc[0][nt] = __builtin_amdgcn_mfma_f32_16x16x32_bf16(ah0, bl[nt], acc[0][nt], 0, 0, 0);
          acc[1][nt] = __builtin_amdgcn_mfma_f32_16x16x32_bf16(ah1, bh[nt], acc[1][nt], 0, 0, 0);
          acc[1][nt] = __builtin_amdgcn_mfma_f32_16x16x32_bf16(al1, bh[nt], acc[1][nt], 0, 0, 0);
          acc[1][nt] = __builtin_amdgcn_mfma_f32_16x16x32_bf16(ah1, bl[nt], acc[1][nt], 0, 0, 0);
        }
      }
    }
    __builtin_amdgcn_s_setprio(0);
    // epilogue: SiLU, mask a<56, reduce over a, write q[eo]
#pragma unroll
    for (int mt = 0; mt < 2; ++mt) {
#pragma unroll
      for (int r = 0; r < 4; ++r) {
        float s = 0.f;
#pragma unroll
        for (int nt = 0; nt < 4; ++nt) {
          float v = silu_f(acc[mt][nt][r]);
          int a = 16 * nt + lm;
          s += (a < A_DIM) ? v : 0.f;
        }
        s += __shfl_xor(s, 1, 64);
        s += __shfl_xor(s, 2, 64);
        s += __shfl_xor(s, 4, 64);
        s += __shfl_xor(s, 8, 64);
        if (lm == 0) {
          int eo = 16 * (2 * w + mt) + lr + r;
          smf[QF + eo] = s * (1.f / 56.f);
        }
      }
    }
  }
  // ---- async-stage: issue x reloads BEFORE the barrier; consume after ----
  float4 vbuf[7];
#pragma unroll
  for (int ii = 0; ii < 7; ++ii) {
    int i = t + ii * 256;                      // 7*256 = 1792 exactly
    int a = i >> 5, e4 = i & 31;
    vbuf[ii] = *(const float4*)(xb + a * 128 + e4 * 4);
  }
  __syncthreads();

  // ====== Phase 3a: LN(q) (t<128) + stage x rows hi/lo over dead h ========
  if (t < 128) {
    float v = smf[QF + t];
    float s = v;
#pragma unroll
    for (int m = 1; m < 16; m <<= 1) s += __shfl_xor(s, m, 64);
    float mean = s * (1.f / 16.f);
    float d = v - mean;
    float s2 = d * d;
#pragma unroll
    for (int m = 1; m < 16; m <<= 1) s2 += __shfl_xor(s2, m, 64);
    float var = s2 * (1.f / 16.f);
    int dd = t & 15;
    float qn = d * rsqrtf(var + 1e-5f) * qn_w[dd] + qn_b[dd];
    smf[QNF + t] = qn * 0.25f;                 // SCALING = 16^-0.5
  }
#pragma unroll
  for (int ii = 0; ii < 7; ++ii) {             // x_row: [a][e] bf16 hi/lo
    int i = t + ii * 256;
    int a = i >> 5, e4 = i & 31;
    float4 v = vbuf[ii];
    unsigned u0 = __float_as_uint(v.x), u1 = __float_as_uint(v.y);
    unsigned u2 = __float_as_uint(v.z), u3 = __float_as_uint(v.w);
    float l0 = v.x - __uint_as_float(u0 & 0xFFFF0000u);
    float l1 = v.y - __uint_as_float(u1 & 0xFFFF0000u);
    float l2 = v.z - __uint_as_float(u2 & 0xFFFF0000u);
    float l3 = v.w - __uint_as_float(u3 & 0xFFFF0000u);
    int off = a * 272 + e4 * 8;
    *(uint2*)(smem + XR_HI_B + off) = make_uint2(pack_hi16(u0, u1), pack_hi16(u2, u3));
    *(uint2*)(smem + XR_LO_B + off) =
        make_uint2(pack_hi16(__float_as_uint(l0), __float_as_uint(l1)),
                   pack_hi16(__float_as_uint(l2), __float_as_uint(l3)));
  }
  __syncthreads();

  // ================= Phase 3b: k-proj (C3^T[o][a]) -> kmat[a][o] ===========
  // A[m=o][k=e] = WK (global hi/lo) ; B[n=a][k=e] = x_row (LDS hi/lo)
  {
    floatx4 acc[2][4];
#pragma unroll
    for (int mt = 0; mt < 2; ++mt)
#pragma unroll
      for (int nt = 0; nt < 4; ++nt) {
        acc[mt][nt][0] = 0.f; acc[mt][nt][1] = 0.f;
        acc[mt][nt][2] = 0.f; acc[mt][nt][3] = 0.f;
      }
    const unsigned char* xrh = smem + XR_HI_B;
    const unsigned char* xrl = smem + XR_LO_B;
    int rofs[4];
#pragma unroll
    for (int nt = 0; nt < 4; ++nt) {
      int a = 16 * nt + lm;
      rofs[nt] = ((a > 55) ? 55 : a) * 272;
    }
    __builtin_amdgcn_s_setprio(1);
#pragma unroll 1
    for (int kc = 0; kc < 4; ++kc) {
      int kob = (kc * 32 + lkg8) * 2;
      const unsigned short* fb = ws + (kc * 8 + 2 * w) * 512 + lm * 32 + lkg8;
      short8 ah0 = *(const short8*)(fb + WKH);
      short8 ah1 = *(const short8*)(fb + WKH + 512);
      short8 al0 = *(const short8*)(fb + WKL);
      short8 al1 = *(const short8*)(fb + WKL + 512);
      short8 bh[4], bl[4];
#pragma unroll
      for (int nt = 0; nt < 4; ++nt) {
        bh[nt] = *(const short8*)(xrh + rofs[nt] + kob);
        bl[nt] = *(const short8*)(xrl + rofs[nt] + kob);
      }
#pragma unroll
      for (int nt = 0; nt < 4; ++nt) {
        acc[0][nt] = __builtin_amdgcn_mfma_f32_16x16x32_bf16(ah0, bh[nt], acc[0][nt], 0, 0, 0);
        acc[0][nt] = __builtin_amdgcn_mfma_f32_16x16x32_bf16(al0, bh[nt], acc[0][nt], 0, 0, 0);
        acc[0][nt] = __builtin_amdgcn_mfma_f32_16x16x32_bf16(ah0, bl[nt], acc[0][nt], 0, 0, 0);
        acc[1][nt] = __builtin_amdgcn_mfma_f32_16x16x32_bf16(ah1, bh[nt], acc[1][nt], 0, 0, 0);
        acc[1][nt] = __builtin_amdgcn_mfma_f32_16x16x32_bf16(al1, bh[nt], acc[1][nt], 0, 0, 0);
        acc[1][nt] = __builtin_amdgcn_mfma_f32_16x16x32_bf16(ah1, bl[nt], acc[1][nt], 0, 0, 0);
      }
    }
    __builtin_amdgcn_s_setprio(0);
    // ---- x_row dead once ALL waves finished reads; kmat overlays it -------
    __syncthreads();
#pragma unroll
    for (int mt = 0; mt < 2; ++mt) {
      int o0 = 16 * (2 * w + mt) + lr;
#pragma unroll
      for (int nt = 0; nt < 4; ++nt) {
        int a = 16 * nt + lm;
        if (a < A_DIM)
          *(floatx4*)&smf[(KM_B / 4) + a * KP2 + o0] = acc[mt][nt];
      }
    }
  }
  __syncthreads();

  // ================= Phase 4: layernorm(k) + logit = qn . kn ===============
  for (int r = 0; r < 2; ++r) {
    int task = t + r * 256;
    if (task < A_DIM * 8) {
      int a = task >> 3, h2 = task & 7;
      float kv[16];
      float s = 0.f;
#pragma unroll
      for (int d = 0; d < 16; ++d) { kv[d] = smf[(KM_B / 4) + a * KP2 + h2 * 16 + d]; s += kv[d]; }
      float mean = s * (1.f / 16.f);
      float s2 = 0.f;
#pragma unroll
      for (int d = 0; d < 16; ++d) { float dd = kv[d] - mean; s2 += dd * dd; }
      float rs = rsqrtf(s2 * (1.f / 16.f) + 1e-5f);
      float logit = 0.f;
#pragma unroll
      for (int d = 0; d < 16; ++d) {
        float kn = (kv[d] - mean) * rs * kn_w[d] + kn_b[d];
        logit += smf[QNF + h2 * 16 + d] * kn;
      }
      smf[LGF + h2 * 60 + a] = logit;
    }
  }
  __syncthreads();

  // ===== Phase 5+6 fused: per-head wave computes both softmaxes + diff =====
  {
    int h = t >> 6;                    // head = wave
    int a = t & 63;
    bool act = (a < A_DIM);
    float lam = smf[LAMF];
    float l0 = act ? smf[LGF + (2 * h) * 60 + a] : -1e30f;
    float l1 = act ? smf[LGF + (2 * h + 1) * 60 + a] : -1e30f;
    float m0 = l0, m1 = l1;
#pragma unroll
    for (int s = 1; s < 64; s <<= 1) {
      m0 = fmaxf(m0, __shfl_xor(m0, s, 64));
      m1 = fmaxf(m1, __shfl_xor(m1, s, 64));
    }
    float e0 = act ? expf(l0 - m0) : 0.f;
    float e1 = act ? expf(l1 - m1) : 0.f;
    float s0 = e0, s1 = e1;
#pragma unroll
    for (int s = 1; s < 64; s <<= 1) {
      s0 += __shfl_xor(s0, s, 64);
      s1 += __shfl_xor(s1, s, 64);
    }
    float p0 = e0 * (1.f / s0);
    float p1 = e1 * (1.f / s1);
    float dlog = act ? (p0 - lam * p1) : -1e30f;
    float m = dlog;
#pragma unroll
    for (int s = 1; s < 64; s <<= 1) m = fmaxf(m, __shfl_xor(m, s, 64));
    float e = act ? expf(dlog - m) : 0.f;
    float ss = e;
#pragma unroll
    for (int s = 1; s < 64; s <<= 1) ss += __shfl_xor(ss, s, 64);
    if (act) smf[DPF + h * 60 + a] = e / ss;
  }
  __syncthreads();

  // ================= Phase 7: mean over heads ==============================
  if (t < A_DIM) {
    float r = 0.25f * (smf[DPF + t] + smf[DPF + 60 + t] +
                       smf[DPF + 120 + t] + smf[DPF + 180 + t]);
    out[(size_t)b * A_DIM + t] = r;
  }
}

extern "C" void kernel_launch(void* const* d_in, const int* in_sizes, int n_in,
                              void* d_out, int out_size, void* d_ws, size_t ws_size,
                              hipStream_t stream) {
  const float* x       = (const float*)d_in[0];
  const float* w_emb   = (const float*)d_in[1];
  const float* b_emb   = (const float*)d_in[2];
  const float* w_atlas = (const float*)d_in[3];
  const float* b_atlas = (const float*)d_in[4];
  const float* w_k     = (const float*)d_in[5];
  const float* qn_w    = (const float*)d_in[6];
  const float* qn_b    = (const float*)d_in[7];
  const float* kn_w    = (const float*)d_in[8];
  const float* kn_b    = (const float*)d_in[9];
  const float* lq1     = (const float*)d_in[10];
  const float* lk1     = (const float*)d_in[11];
  const float* lq2     = (const float*)d_in[12];
  const float* lk2     = (const float*)d_in[13];
  float* out = (float*)d_out;
  unsigned short* ws = (unsigned short*)d_ws;

  prep_weights<<<dim3((PREP_ELEMS + 255) / 256), dim3(256), 0, stream>>>(
      w_emb, w_atlas, w_k, ws);

  const int Bn = in_sizes[0] / (A_DIM * E_DIM);   // 8192
  atlas_fused<<<dim3(Bn), dim3(256), 0, stream>>>(
      x, ws, b_emb, b_atlas, qn_w, qn_b, kn_w, kn_b,
      lq1, lk1, lq2, lk2, out);
}